// Round 3
// baseline (1002.678 us; speedup 1.0000x reference)
//
#include <hip/hip_runtime.h>

// GeodesicLoss: outputs(B,D) f32, targets(B,D) f32, gamma(B,D,D,D) f32 -> scalar f32
// B=256, D=64, NUM_STEPS=10 (RK2 midpoint).
// Register-resident design: 1 block per batch (256 blocks = 1/CU). Symmetrized
// packed gamma (64 rows x 2080 -> padded 2304) lives in VGPRs: each of 16 waves
// owns 4 rows, 9 float4 chunks per lane (144 VGPRs). Gamma is read from HBM
// exactly once; all 20 accel passes run from registers + 9KB LDS wp buffer.

#define NSTEPS 10
#define BATCH 256
#define DIM 64
#define TPB 1024
#define RBS 65                    // padded staging stride (bank-conflict-free)
#define RBF (DIM * RBS)           // 4160 floats per staged row
#define NPACK 2080                // D*(D+1)/2
#define NPADF 2304                // padded packed row: 576 f4 = 9 chunks/lane
#define NCH 9

__device__ __forceinline__ float waveSum(float v) {
    #pragma unroll
    for (int off = 32; off; off >>= 1) v += __shfl_xor(v, off, 64);
    return v;
}

__device__ __forceinline__ void unpack_e(int e, int& j, int& k) {
    int jj = 0;
    while (e >= DIM - jj) { e -= DIM - jj; ++jj; }
    j = jj; k = jj + e;
}

__device__ __forceinline__ float symf(const float* rb, int j, int k) {
    float v = rb[j * RBS + k];
    if (j != k) v += rb[k * RBS + j];
    return v;
}

__global__ void init_ws_kernel(unsigned* ws) {
    if (threadIdx.x < 4) ws[threadIdx.x] = 0u;   // [0]=geo, [1]=euclid, [2]=flag
}

__global__ __launch_bounds__(TPB, 1)
void geo_main_kernel(const float* __restrict__ x0g,
                     const float* __restrict__ x1g,
                     const float* __restrict__ gam,
                     float* __restrict__ ws)
{
    __shared__ float rowbuf[2 * RBF];     // 33.3 KB: raw-row staging (padded)
    __shared__ float pkbuf[2 * NPADF];    // 18.4 KB: packed staging / wp buffer
    __shared__ float vel[DIM], mvel[DIM], acc[DIM];

    const int b    = blockIdx.x;
    const int t    = threadIdx.x;
    const int wave = t >> 6;
    const int lane = t & 63;
    const float dt = 1.0f / NSTEPS;

    // ---- per-thread packed-index LUT (e -> (j,k)), computed once ----
    int j0, k0, j1, k1, j2 = 0, k2 = 0;
    unpack_e(t,        j0, k0);            // e0 = t        (always < 2080)
    unpack_e(t + 1024, j1, k1);            // e1 = t+1024   (always < 2080)
    if (t < 32) unpack_e(t + 2048, j2, k2);// e2 real only for t < 32

    // ---- wave 0: initial velocity, euclid contribution ----
    float x1r = 0.f, fpPrev = 0.f, fpCur = 0.f, trajr = 0.f;
    if (wave == 0) {
        float x0r = x0g[b * DIM + lane];
        x1r       = x1g[b * DIM + lane];
        float d0  = x1r - x0r;
        float nrm = sqrtf(waveSum(d0 * d0));
        if (lane == 0) atomicAdd(&ws[1], nrm * (1.0f / BATCH));
        float v  = d0 * dt;
        float nv = nrm * dt;
        vel[lane] = v / (nv + 1e-8f);
        trajr = x0r;
        fpCur = x0r;
    }

    // ---- load + symmetrize gamma into registers (HBM read: exactly once) ----
    float4 gm[4][NCH];                     // 144 VGPRs resident packed gamma
    unsigned nzflag = 0;
    const float4* g4 = (const float4*)(gam + (size_t)b * DIM * DIM * DIM);

    float4 pre0 = g4[t];
    float4 pre1 = g4[1024 + t];
    #pragma unroll
    for (int ip = 0; ip < 32; ++ip) {      // rows i0=2ip, i1=2ip+1
        // A: stage both raw rows into padded LDS (scalar stores, ~2-way free)
        {
            float* d0p = rowbuf +       (t >> 4) * RBS + ((t & 15) << 2);
            float* d1p = rowbuf + RBF + (t >> 4) * RBS + ((t & 15) << 2);
            d0p[0] = pre0.x; d0p[1] = pre0.y; d0p[2] = pre0.z; d0p[3] = pre0.w;
            d1p[0] = pre1.x; d1p[1] = pre1.y; d1p[2] = pre1.z; d1p[3] = pre1.w;
            nzflag |= (pre0.x != 0.f) | (pre0.y != 0.f) | (pre0.z != 0.f) | (pre0.w != 0.f)
                    | (pre1.x != 0.f) | (pre1.y != 0.f) | (pre1.z != 0.f) | (pre1.w != 0.f);
        }
        __syncthreads();
        // B: prefetch next row pair; build packed rows in LDS
        if (ip + 1 < 32) {
            pre0 = g4[(size_t)(2 * ip + 2) * 1024 + t];
            pre1 = g4[(size_t)(2 * ip + 3) * 1024 + t];
        }
        {
            const float* rb0 = rowbuf;
            const float* rb1 = rowbuf + RBF;
            float* pk0 = pkbuf;
            float* pk1 = pkbuf + NPADF;
            pk0[t]        = symf(rb0, j0, k0);
            pk1[t]        = symf(rb1, j0, k0);
            pk0[t + 1024] = symf(rb0, j1, k1);
            pk1[t + 1024] = symf(rb1, j1, k1);
            if (t < 32) {
                pk0[t + 2048] = symf(rb0, j2, k2);
                pk1[t + 2048] = symf(rb1, j2, k2);
            } else if (t < 256) {
                pk0[t + 2048] = 0.f;
                pk1[t + 2048] = 0.f;
            }
        }
        __syncthreads();
        // C: owner wave copies packed rows into registers (static indices)
        if (wave == (ip >> 1)) {
            const float4* pk40 = (const float4*)pkbuf;
            const float4* pk41 = (const float4*)(pkbuf + NPADF);
            const int r0 = (ip & 1) * 2;
            #pragma unroll
            for (int u = 0; u < NCH; ++u) gm[r0][u]     = pk40[lane + (u << 6)];
            #pragma unroll
            for (int u = 0; u < NCH; ++u) gm[r0 + 1][u] = pk41[lane + (u << 6)];
        }
        // no barrier here: next B-phase writes pkbuf only after next sync
    }
    __syncthreads();

    // ---- accel from registers: wp (LDS, aliases pkbuf) built cooperatively ----
    float* wp = pkbuf;
    auto accel = [&](const float* vsrc) {
        // contract: vsrc valid & previous wp consumers done (caller's barrier)
        wp[t]        = vsrc[j0] * vsrc[k0];
        wp[t + 1024] = vsrc[j1] * vsrc[k1];
        if (t < 32)       wp[t + 2048] = vsrc[j2] * vsrc[k2];
        else if (t < 256) wp[t + 2048] = 0.f;
        __syncthreads();
        const float4* wp4 = (const float4*)wp;
        float s0 = 0.f, s1 = 0.f, s2 = 0.f, s3 = 0.f;
        #pragma unroll
        for (int u = 0; u < NCH; ++u) {
            float4 w = wp4[lane + (u << 6)];
            s0 += gm[0][u].x * w.x + gm[0][u].y * w.y + gm[0][u].z * w.z + gm[0][u].w * w.w;
            s1 += gm[1][u].x * w.x + gm[1][u].y * w.y + gm[1][u].z * w.z + gm[1][u].w * w.w;
            s2 += gm[2][u].x * w.x + gm[2][u].y * w.y + gm[2][u].z * w.z + gm[2][u].w * w.w;
            s3 += gm[3][u].x * w.x + gm[3][u].y * w.y + gm[3][u].z * w.z + gm[3][u].w * w.w;
        }
        s0 = waveSum(s0); s1 = waveSum(s1); s2 = waveSum(s2); s3 = waveSum(s3);
        if (lane == 0) {
            const int i0 = wave << 2;
            acc[i0] = -s0; acc[i0 + 1] = -s1; acc[i0 + 2] = -s2; acc[i0 + 3] = -s3;
        }
        __syncthreads();
    };

    // ---- RK2 integration (all from registers + tiny LDS state) ----
    float smooth = 0.f;
    for (int s = 0; s < NSTEPS; ++s) {
        accel(vel);                                      // a1 = A(vel)
        if (wave == 0) mvel[lane] = vel[lane] + 0.5f * dt * acc[lane];
        __syncthreads();
        accel(mvel);                                     // a2 = A(mid_vel)
        if (wave == 0) {
            float vnew = vel[lane] + dt * acc[lane];
            vel[lane]  = vnew;
            float fpNext = trajr + dt * vnew;
            trajr = fpNext;
            if (s >= 1) {
                float sec = fpNext - 2.f * fpCur + fpPrev;
                smooth += sqrtf(waveSum(sec * sec));
            }
            fpPrev = fpCur;
            fpCur  = fpNext;
        }
        __syncthreads();
    }

    // ---- nonzero flag ----
    unsigned long long bal = __ballot(nzflag != 0);
    if (lane == 0 && bal) atomicOr((unsigned*)ws + 2, 1u);

    // ---- per-batch geodesic contribution ----
    if (wave == 0) {
        float dl  = trajr - x1r;
        float tgt = sqrtf(waveSum(dl * dl));
        if (lane == 0) atomicAdd(&ws[0], (tgt + 0.1f * smooth) * (1.0f / BATCH));
    }
}

__global__ void finalize_kernel(const float* ws, float* out) {
    unsigned flag = ((const unsigned*)ws)[2];
    out[0] = flag ? ws[0] : ws[1];
}

extern "C" void kernel_launch(void* const* d_in, const int* in_sizes, int n_in,
                              void* d_out, int out_size, void* d_ws, size_t ws_size,
                              hipStream_t stream) {
    const float* x0  = (const float*)d_in[0];   // outputs
    const float* x1  = (const float*)d_in[1];   // targets
    const float* gam = (const float*)d_in[2];   // christoffel_symbols
    float* ws = (float*)d_ws;                    // 4-word accumulator header only

    init_ws_kernel<<<1, 64, 0, stream>>>((unsigned*)ws);
    geo_main_kernel<<<BATCH, TPB, 0, stream>>>(x0, x1, gam, ws);
    finalize_kernel<<<1, 1, 0, stream>>>(ws, (float*)d_out);
}

// Round 4
// 613.447 us; speedup vs baseline: 1.6345x; 1.6345x over previous
//
#include <hip/hip_runtime.h>

// GeodesicLoss: outputs(B,D) f32, targets(B,D) f32, gamma(B,D,D,D) f32 -> scalar f32
// B=256, D=64, NUM_STEPS=10 (RK2 midpoint).
// Fully on-chip design: 256 blocks x 512 threads (1 block/CU, VGPR cap 256).
// Symmetrized gamma via d-fold: pair (j,k) -> e = d*64+j, d=(k-j)&63 in [0,32),
// main 2048 floats/row; d=32 tail 32 floats/row. Residency: 48 rows in VGPRs
// (6/wave x 8 float4), 16 rows + all tails in LDS. Gamma read from HBM ONCE.

#define NSTEPS 10
#define BATCH 256
#define DIM 64
#define TPB 512
#define REGROWS 6
#define NREGTOT 48               // REGROWS * 8 waves
#define RBS 65                   // padded staging stride
#define MAINF 2048
#define TAILF 32

__device__ __forceinline__ float waveSum(float v) {
    #pragma unroll
    for (int off = 32; off; off >>= 1) v += __shfl_xor(v, off, 64);
    return v;
}

__global__ void init_ws_kernel(unsigned* ws) {
    if (threadIdx.x < 4) ws[threadIdx.x] = 0u;   // [0]=geo, [1]=euclid, [2]=flag
}

__global__ __launch_bounds__(TPB, 2)
void geo_main_kernel(const float* __restrict__ x0g,
                     const float* __restrict__ x1g,
                     const float* __restrict__ gam,
                     float* __restrict__ ws)
{
    __shared__ float ldsg[16][MAINF];            // 131072 B: rows 48..63 main
    __shared__ float tails[DIM][TAILF];          //   8192 B: all rows' d=32 tails
    __shared__ __align__(16) char ubuf[16640];   //  16640 B: rowbuf (load) / wp+state (integ)

    float* const rowbuf = (float*)ubuf;                 // load phase: 64x65 staging
    float* const wp     = (float*)ubuf;                 // integ: 2080 outer-product
    float* const vel    = (float*)(ubuf + 8320);
    float* const mvel   = (float*)(ubuf + 8576);
    float* const acc    = (float*)(ubuf + 8832);
    float* const xfer   = ldsg[15];                     // load-phase reg-row handoff

    const int b    = blockIdx.x;
    const int t    = threadIdx.x;
    const int wave = t >> 6;
    const int lane = t & 63;
    const float dt = 1.0f / NSTEPS;

    float4 gm[REGROWS][8];                       // 192 VGPRs: 6 rows/wave resident
    unsigned nzflag = 0;

    const float4* g4 = (const float4*)(gam + (size_t)b * DIM * DIM * DIM);

    // depth-2 row prefetch
    float4 pA0 = g4[t],        pA1 = g4[512 + t];          // row 0
    float4 pB0 = g4[1024 + t], pB1 = g4[1536 + t];         // row 1

    const int st0 = (t >> 4) * RBS + ((t & 15) << 2);
    const int st1 = ((t + 512) >> 4) * RBS + (((t + 512) & 15) << 2);

    #pragma unroll
    for (int i = 0; i < DIM; ++i) {
        // ---- phase A: stage row i into padded rowbuf; owner-read row i-1 ----
        {
            const float4 c0 = (i & 1) ? pB0 : pA0;
            const float4 c1 = (i & 1) ? pB1 : pA1;
            rowbuf[st0] = c0.x; rowbuf[st0+1] = c0.y; rowbuf[st0+2] = c0.z; rowbuf[st0+3] = c0.w;
            rowbuf[st1] = c1.x; rowbuf[st1+1] = c1.y; rowbuf[st1+2] = c1.z; rowbuf[st1+3] = c1.w;
            nzflag |= (c0.x != 0.f) | (c0.y != 0.f) | (c0.z != 0.f) | (c0.w != 0.f)
                    | (c1.x != 0.f) | (c1.y != 0.f) | (c1.z != 0.f) | (c1.w != 0.f);
        }
        if (i >= 1 && (i - 1) < NREGTOT) {
            const int ow  = (i - 1) / REGROWS;
            const int orr = (i - 1) % REGROWS;           // compile-time (full unroll)
            if (wave == ow) {
                const float4* x4 = (const float4*)xfer;
                #pragma unroll
                for (int u = 0; u < 8; ++u) gm[orr][u] = x4[lane + (u << 6)];
            }
        }
        __syncthreads();
        // ---- phase B: prefetch row i+2; build folded row i ----
        if (i + 2 < DIM) {
            if (i & 1) { pB0 = g4[(size_t)(i + 2) * 1024 + t]; pB1 = g4[(size_t)(i + 2) * 1024 + 512 + t]; }
            else       { pA0 = g4[(size_t)(i + 2) * 1024 + t]; pA1 = g4[(size_t)(i + 2) * 1024 + 512 + t]; }
        }
        {
            float* const dst = (i < NREGTOT) ? xfer : ldsg[i - NREGTOT];  // static per i
            #pragma unroll
            for (int rep = 0; rep < 4; ++rep) {
                const int e = t + rep * TPB;             // e < 2048
                const int j = e & 63, d = e >> 6, k = (j + d) & 63;
                float v = rowbuf[j * RBS + k];
                if (d > 0) v += rowbuf[k * RBS + j];
                dst[e] = v;
            }
            if (t < TAILF)
                tails[i][t] = rowbuf[t * RBS + (t + 32)] + rowbuf[(t + 32) * RBS + t];
        }
        __syncthreads();
    }

    // ---- wave 0: initial velocity, euclid; all: nz flag ----
    float x1r = 0.f, fpPrev = 0.f, fpCur = 0.f, trajr = 0.f, smooth = 0.f;
    if (wave == 0) {
        float x0r = x0g[b * DIM + lane];
        x1r       = x1g[b * DIM + lane];
        float dd  = x1r - x0r;
        float nrm = sqrtf(waveSum(dd * dd));
        if (lane == 0) atomicAdd(&ws[1], nrm * (1.0f / BATCH));
        float v = dd * dt, nv = nrm * dt;
        vel[lane] = v / (nv + 1e-8f);
        trajr = x0r; fpCur = x0r;
    }
    unsigned long long bal = __ballot(nzflag != 0);
    if (lane == 0 && bal) atomicOr((unsigned*)ws + 2, 1u);
    __syncthreads();

    const float4* const wp4    = (const float4*)wp;
    const float4* const wpt4   = (const float4*)(wp + MAINF);
    const float4* const tails4 = (const float4*)tails;

    auto accel = [&](const float* vsrc) {
        #pragma unroll
        for (int rep = 0; rep < 4; ++rep) {
            const int e = t + rep * TPB;
            const int j = e & 63, d = e >> 6, k = (j + d) & 63;
            wp[e] = vsrc[j] * vsrc[k];
        }
        if (t < TAILF) wp[MAINF + t] = vsrc[t] * vsrc[t + 32];
        __syncthreads();

        float s0=0.f,s1=0.f,s2=0.f,s3=0.f,s4=0.f,s5=0.f,s6=0.f,s7=0.f;
        const float4* const e0 = (const float4*)ldsg[2 * wave];
        const float4* const e1 = (const float4*)ldsg[2 * wave + 1];
        #pragma unroll
        for (int u = 0; u < 8; ++u) {
            const float4 w = wp4[lane + (u << 6)];
            s0 += gm[0][u].x*w.x + gm[0][u].y*w.y + gm[0][u].z*w.z + gm[0][u].w*w.w;
            s1 += gm[1][u].x*w.x + gm[1][u].y*w.y + gm[1][u].z*w.z + gm[1][u].w*w.w;
            s2 += gm[2][u].x*w.x + gm[2][u].y*w.y + gm[2][u].z*w.z + gm[2][u].w*w.w;
            s3 += gm[3][u].x*w.x + gm[3][u].y*w.y + gm[3][u].z*w.z + gm[3][u].w*w.w;
            s4 += gm[4][u].x*w.x + gm[4][u].y*w.y + gm[4][u].z*w.z + gm[4][u].w*w.w;
            s5 += gm[5][u].x*w.x + gm[5][u].y*w.y + gm[5][u].z*w.z + gm[5][u].w*w.w;
            const float4 a0 = e0[lane + (u << 6)];
            const float4 a1 = e1[lane + (u << 6)];
            s6 += a0.x*w.x + a0.y*w.y + a0.z*w.z + a0.w*w.w;
            s7 += a1.x*w.x + a1.y*w.y + a1.z*w.z + a1.w*w.w;
        }
        if (lane < 8) {
            const float4 wt = wpt4[lane];
            float4 a;
            a = tails4[(6*wave+0)*8 + lane]; s0 += a.x*wt.x + a.y*wt.y + a.z*wt.z + a.w*wt.w;
            a = tails4[(6*wave+1)*8 + lane]; s1 += a.x*wt.x + a.y*wt.y + a.z*wt.z + a.w*wt.w;
            a = tails4[(6*wave+2)*8 + lane]; s2 += a.x*wt.x + a.y*wt.y + a.z*wt.z + a.w*wt.w;
            a = tails4[(6*wave+3)*8 + lane]; s3 += a.x*wt.x + a.y*wt.y + a.z*wt.z + a.w*wt.w;
            a = tails4[(6*wave+4)*8 + lane]; s4 += a.x*wt.x + a.y*wt.y + a.z*wt.z + a.w*wt.w;
            a = tails4[(6*wave+5)*8 + lane]; s5 += a.x*wt.x + a.y*wt.y + a.z*wt.z + a.w*wt.w;
            a = tails4[(48+2*wave)*8 + lane]; s6 += a.x*wt.x + a.y*wt.y + a.z*wt.z + a.w*wt.w;
            a = tails4[(49+2*wave)*8 + lane]; s7 += a.x*wt.x + a.y*wt.y + a.z*wt.z + a.w*wt.w;
        }
        s0 = waveSum(s0); s1 = waveSum(s1); s2 = waveSum(s2); s3 = waveSum(s3);
        s4 = waveSum(s4); s5 = waveSum(s5); s6 = waveSum(s6); s7 = waveSum(s7);
        if (lane == 0) {
            acc[6*wave+0] = -s0; acc[6*wave+1] = -s1; acc[6*wave+2] = -s2;
            acc[6*wave+3] = -s3; acc[6*wave+4] = -s4; acc[6*wave+5] = -s5;
            acc[48 + 2*wave] = -s6; acc[49 + 2*wave] = -s7;
        }
        __syncthreads();
    };

    // ---- RK2 integration: 20 accel passes entirely from VGPR/LDS ----
    #pragma unroll 1
    for (int st = 0; st < NSTEPS; ++st) {
        accel(vel);                                       // a1 = A(vel)
        if (wave == 0) mvel[lane] = vel[lane] + 0.5f * dt * acc[lane];
        __syncthreads();
        accel(mvel);                                      // a2 = A(mid_vel)
        if (wave == 0) {
            float vnew = vel[lane] + dt * acc[lane];
            vel[lane]  = vnew;
            float fpNext = trajr + dt * vnew;
            trajr = fpNext;
            if (st >= 1) {
                float sec = fpNext - 2.f * fpCur + fpPrev;
                smooth += sqrtf(waveSum(sec * sec));
            }
            fpPrev = fpCur;
            fpCur  = fpNext;
        }
        __syncthreads();
    }

    // ---- per-batch geodesic contribution ----
    if (wave == 0) {
        float dl  = trajr - x1r;
        float tgt = sqrtf(waveSum(dl * dl));
        if (lane == 0) atomicAdd(&ws[0], (tgt + 0.1f * smooth) * (1.0f / BATCH));
    }
}

__global__ void finalize_kernel(const float* ws, float* out) {
    unsigned flag = ((const unsigned*)ws)[2];
    out[0] = flag ? ws[0] : ws[1];
}

extern "C" void kernel_launch(void* const* d_in, const int* in_sizes, int n_in,
                              void* d_out, int out_size, void* d_ws, size_t ws_size,
                              hipStream_t stream) {
    const float* x0  = (const float*)d_in[0];   // outputs
    const float* x1  = (const float*)d_in[1];   // targets
    const float* gam = (const float*)d_in[2];   // christoffel_symbols
    float* ws = (float*)d_ws;                    // 4-word accumulator header

    init_ws_kernel<<<1, 64, 0, stream>>>((unsigned*)ws);
    geo_main_kernel<<<BATCH, TPB, 0, stream>>>(x0, x1, gam, ws);
    finalize_kernel<<<1, 1, 0, stream>>>(ws, (float*)d_out);
}